// Round 9
// baseline (264.133 us; speedup 1.0000x reference)
//
#include <hip/hip_runtime.h>
#include <math.h>

#define B_   2
#define S_   1024
#define HID_ 2048
#define HQ_  32
#define HKV_ 8
#define HD_  64

using short8  = __attribute__((ext_vector_type(8))) short;
using floatx4 = __attribute__((ext_vector_type(4))) float;

__device__ __forceinline__ unsigned short f2bf(float x) {
    unsigned int u = __builtin_bit_cast(unsigned int, x);
    u += 0x7FFFu + ((u >> 16) & 1u);
    return (unsigned short)(u >> 16);
}
__device__ __forceinline__ float bf2f(unsigned short u) {
    return __builtin_bit_cast(float, (unsigned int)u << 16);
}

__device__ __forceinline__ void gl_lds16(const unsigned short* g, unsigned short* l) {
    __builtin_amdgcn_global_load_lds(
        (const __attribute__((address_space(1))) void*)g,
        (__attribute__((address_space(3))) void*)l, 16, 0, 0);
}

// ---------------------------------------------------------------------------
// PREP (one kernel): convert_x + transpose Wq|Wk|Wv -> WcatT + Wo -> WoT.
// bid ranges: [0,4096) x-convert; [4096,10240) qkv transpose; [10240,14336) wo.
// ---------------------------------------------------------------------------
__global__ __launch_bounds__(256) void prep_all(const float* __restrict__ X,
                                                const float* __restrict__ Wq,
                                                const float* __restrict__ Wk,
                                                const float* __restrict__ Wv,
                                                const float* __restrict__ Wo,
                                                unsigned short* __restrict__ Xbf,
                                                unsigned short* __restrict__ WcatT,
                                                unsigned short* __restrict__ WoT) {
    __shared__ float tile[32][33];
    int bid = blockIdx.x;
    if (bid < 4096) {
        int tid = bid * 256 + threadIdx.x;
        float4 v = *(const float4*)&X[(size_t)tid * 4];
        ushort4 o = {f2bf(v.x), f2bf(v.y), f2bf(v.z), f2bf(v.w)};
        *(ushort4*)&Xbf[(size_t)tid * 4] = o;
        return;
    }
    const float* W;
    unsigned short* WT;
    int N, tn0, tk0;
    if (bid < 10240) {
        bid -= 4096;
        if (bid < 4096) {
            W = Wq; WT = WcatT; N = HID_;
            tn0 = (bid & 63) * 32; tk0 = (bid >> 6) * 32;
        } else if (bid < 5120) {
            bid -= 4096;
            W = Wk; WT = WcatT + (size_t)HID_ * HID_; N = 512;
            tn0 = (bid & 15) * 32; tk0 = (bid >> 4) * 32;
        } else {
            bid -= 5120;
            W = Wv; WT = WcatT + (size_t)(HID_ + 512) * HID_; N = 512;
            tn0 = (bid & 15) * 32; tk0 = (bid >> 4) * 32;
        }
    } else {
        bid -= 10240;
        W = Wo; WT = WoT; N = HID_;
        tn0 = (bid & 63) * 32; tk0 = (bid >> 6) * 32;
    }
    const int r  = threadIdx.x >> 3;
    const int c4 = (threadIdx.x & 7) * 4;
    float4 v = *(const float4*)&W[(size_t)(tk0 + r) * N + tn0 + c4];
    tile[r][c4 + 0] = v.x;
    tile[r][c4 + 1] = v.y;
    tile[r][c4 + 2] = v.z;
    tile[r][c4 + 3] = v.w;
    __syncthreads();
    ushort4 o = {f2bf(tile[c4 + 0][r]), f2bf(tile[c4 + 1][r]),
                 f2bf(tile[c4 + 2][r]), f2bf(tile[c4 + 3][r])};
    *(ushort4*)&WT[(size_t)(tn0 + r) * HID_ + tk0 + c4] = o;
}

// ---------------------------------------------------------------------------
// QKV GEMM, single-K, 64x128 tiles (768 blocks = 3/CU), FUSED RoPE epilogue.
// 4 waves in 2x2 over (32,64): wm=(w>>1)*32, wn=(w&1)*64; 8 MFMAs/K-step.
// LDS: chunk-major regions of 16 rows (512 shorts): addr = reg*512 +
// chunk*128 + row16*8  -> conflict-free b128 fragment reads.
// Epilogue: n0<2048 -> Q (RoPE, *0.125, head-major); n0<2560 -> K (RoPE);
// else V natural head-major [b][kv][s][d].
// ---------------------------------------------------------------------------
__global__ __launch_bounds__(256) void gemm_qkv(const unsigned short* __restrict__ A,
                                                const unsigned short* __restrict__ Bt,
                                                const float* __restrict__ cosT,
                                                const float* __restrict__ sinT,
                                                unsigned short* __restrict__ Qbf,
                                                unsigned short* __restrict__ Kbf,
                                                unsigned short* __restrict__ Vnat) {
    __shared__ __align__(16) unsigned short As[64 * 32];
    __shared__ __align__(16) unsigned short Bs[128 * 32];

    const int m0 = (blockIdx.x / 24) * 64;
    const int n0 = (blockIdx.x % 24) * 128;

    const int tid  = threadIdx.x;
    const int w    = tid >> 6;
    const int lane = tid & 63;
    const int col  = lane & 15;
    const int quad = lane >> 4;
    const int wm = (w >> 1) * 32;
    const int wn = (w & 1) * 64;

    const int lane16 = lane & 15;
    const int lchunk = lane >> 4;
    const unsigned short* Ag  = A  + (size_t)(m0 + 16 * w + lane16) * HID_ + lchunk * 8;
    const unsigned short* Bg0 = Bt + (size_t)(n0 + 16 * w + lane16) * HID_ + lchunk * 8;
    const unsigned short* Bg1 = Bt + (size_t)(n0 + 64 + 16 * w + lane16) * HID_ + lchunk * 8;

    floatx4 acc[2][4] = {};

    for (int k0 = 0; k0 < HID_; k0 += 32) {
        gl_lds16(Ag  + k0, &As[w * 512]);
        gl_lds16(Bg0 + k0, &Bs[w * 512]);
        gl_lds16(Bg1 + k0, &Bs[(4 + w) * 512]);
        __syncthreads();

        short8 af[2], bfr[4];
#pragma unroll
        for (int i = 0; i < 2; ++i)
            af[i] = *(const short8*)&As[((w >> 1) * 2 + i) * 512 + quad * 128 + col * 8];
#pragma unroll
        for (int j = 0; j < 4; ++j)
            bfr[j] = *(const short8*)&Bs[((w & 1) * 4 + j) * 512 + quad * 128 + col * 8];
#pragma unroll
        for (int i = 0; i < 2; ++i)
#pragma unroll
            for (int j = 0; j < 4; ++j)
                acc[i][j] = __builtin_amdgcn_mfma_f32_16x16x32_bf16(
                    af[i], bfr[j], acc[i][j], 0, 0, 0);
        __syncthreads();
    }

    // ---- epilogue ----
    if (n0 < 2048) {                 // Q: RoPE + scale, head-major
        const int h = (n0 + wn) >> 6;
#pragma unroll
        for (int i = 0; i < 2; ++i)
#pragma unroll
            for (int r = 0; r < 4; ++r) {
                int srow = m0 + wm + i * 16 + quad * 4 + r;
                int b = srow >> 10, s = srow & 1023;
                unsigned short* base = Qbf + ((size_t)(b * HQ_ + h) * S_ + s) * HD_;
#pragma unroll
                for (int j = 0; j < 2; ++j) {
                    int d = j * 16 + col;
                    float x0 = acc[i][j][r], x1 = acc[i][j + 2][r];
                    float c0 = cosT[s * HD_ + d],      s0c = sinT[s * HD_ + d];
                    float c1 = cosT[s * HD_ + d + 32], s1c = sinT[s * HD_ + d + 32];
                    base[d]      = f2bf((x0 * c0 - x1 * s0c) * 0.125f);
                    base[d + 32] = f2bf((x1 * c1 + x0 * s1c) * 0.125f);
                }
            }
    } else if (n0 < 2560) {          // K: RoPE, head-major
        const int kvh = (n0 - 2048 + wn) >> 6;
#pragma unroll
        for (int i = 0; i < 2; ++i)
#pragma unroll
            for (int r = 0; r < 4; ++r) {
                int srow = m0 + wm + i * 16 + quad * 4 + r;
                int b = srow >> 10, s = srow & 1023;
                unsigned short* base = Kbf + ((size_t)(b * HKV_ + kvh) * S_ + s) * HD_;
#pragma unroll
                for (int j = 0; j < 2; ++j) {
                    int d = j * 16 + col;
                    float x0 = acc[i][j][r], x1 = acc[i][j + 2][r];
                    float c0 = cosT[s * HD_ + d],      s0c = sinT[s * HD_ + d];
                    float c1 = cosT[s * HD_ + d + 32], s1c = sinT[s * HD_ + d + 32];
                    base[d]      = f2bf(x0 * c0 - x1 * s0c);
                    base[d + 32] = f2bf(x1 * c1 + x0 * s1c);
                }
            }
    } else {                         // V: natural head-major [b][kv][s][d]
        const int kvh = (n0 - 2560 + wn) >> 6;
#pragma unroll
        for (int i = 0; i < 2; ++i)
#pragma unroll
            for (int r = 0; r < 4; ++r) {
                int srow = m0 + wm + i * 16 + quad * 4 + r;
                int b = srow >> 10, s = srow & 1023;
                unsigned short* base = Vnat + ((size_t)(b * HKV_ + kvh) * S_ + s) * HD_;
#pragma unroll
                for (int j = 0; j < 4; ++j)
                    base[j * 16 + col] = f2bf(acc[i][j][r]);
            }
    }
}

// ---------------------------------------------------------------------------
// V transpose: Vnat [b][kv][s][d] -> Vt [b][kv][d][s].  256 blocks.
// ---------------------------------------------------------------------------
__global__ __launch_bounds__(256) void convert_vt(const unsigned short* __restrict__ Vnat,
                                                  unsigned short* __restrict__ Vt) {
    __shared__ unsigned short tile[64][72];   // stride 72 shorts (16B-aligned rows)
    const int bkv = blockIdx.x >> 4;          // b*8+kv
    const int s0  = (blockIdx.x & 15) * 64;
    const int tid = threadIdx.x;
    const int row = tid >> 2;                 // 0..63
    const int dp  = (tid & 3) * 16;

    const unsigned short* src = Vnat + ((size_t)bkv * S_ + s0 + row) * HD_ + dp;
#pragma unroll
    for (int j = 0; j < 16; ++j)
        tile[dp + j][row] = src[j];
    __syncthreads();

    unsigned short* dst = Vt + ((size_t)bkv * HD_ + row) * S_ + s0 + dp;
    *(short8*)&dst[0] = *(const short8*)&tile[row][dp];
    *(short8*)&dst[8] = *(const short8*)&tile[row][dp + 8];
}

// ---------------------------------------------------------------------------
// Flash attention (GEMM-shaped, 4 q-heads share one kv head's LDS K/V).
// Changes vs R8: (1) t scrambled so co-resident blocks on a CU get q-tiles
// spaced 16 apart (load balance); (2) chunk-major LDS staging -> conflict-free
// fragment reads.
// ---------------------------------------------------------------------------
__global__ __launch_bounds__(256) void attn_mfma(const unsigned short* __restrict__ Qbf,
                                                 const unsigned short* __restrict__ Kbf,
                                                 const unsigned short* __restrict__ Vt,
                                                 unsigned short* __restrict__ Ctx) {
    const int t = 63 - ((blockIdx.x + 4 * (blockIdx.y + 8 * blockIdx.z)) & 63);
    const int kv = blockIdx.y;
    const int b  = blockIdx.z;
    const int w    = threadIdx.x >> 6;
    const int lane = threadIdx.x & 63;
    const int col  = lane & 15;
    const int quad = lane >> 4;

    const int h   = kv * 4 + w;
    const int bh  = b * HQ_ + h;
    const int bkv = b * HKV_ + kv;
    const int qw  = 16 * t;
    const int myq = qw + col;

    __shared__ __align__(16) unsigned short sK0[64 * 32];
    __shared__ __align__(16) unsigned short sK1[64 * 32];
    __shared__ __align__(16) unsigned short sV0[64 * 32];
    __shared__ __align__(16) unsigned short sV1[64 * 32];
    __shared__ __align__(16) unsigned short sP[4][16 * 72];
    unsigned short* myP = sP[w];

    const unsigned short* qrow = Qbf + ((size_t)bh * S_ + qw + col) * HD_;
    short8 bq0 = *(const short8*)&qrow[quad * 8];
    short8 bq1 = *(const short8*)&qrow[32 + quad * 8];

    const int lane16 = lane & 15;
    const int lchunk = lane >> 4;
    // K: row = key (k0 + 16w + lane16), chunk = lchunk (d-shorts)
    const unsigned short* KbL =
        Kbf + (size_t)bkv * S_ * HD_ + (size_t)(16 * w + lane16) * HD_ + lchunk * 8;
    // V^T: row = d (16w + lane16), chunk = lchunk (s-shorts)
    const unsigned short* VbL =
        Vt + (size_t)bkv * HD_ * S_ + (size_t)(16 * w + lane16) * S_ + lchunk * 8;

    floatx4 acc[4] = {};
    float m_i = -1e30f, l_i = 0.f;
    const int nsteps = (16 * t + 79) >> 6;

    for (int it = 0; it < nsteps; ++it) {
        const int k0 = it * 64;
        gl_lds16(KbL + (size_t)k0 * HD_,      &sK0[w * 512]);
        gl_lds16(KbL + (size_t)k0 * HD_ + 32, &sK1[w * 512]);
        gl_lds16(VbL + k0,                    &sV0[w * 512]);
        gl_lds16(VbL + k0 + 32,               &sV1[w * 512]);
        __syncthreads();

        floatx4 sc[4];
#pragma unroll
        for (int tt = 0; tt < 4; ++tt) {
            short8 ak0 = *(const short8*)&sK0[tt * 512 + quad * 128 + col * 8];
            short8 ak1 = *(const short8*)&sK1[tt * 512 + quad * 128 + col * 8];
            floatx4 z = {0.f, 0.f, 0.f, 0.f};
            z = __builtin_amdgcn_mfma_f32_16x16x32_bf16(ak0, bq0, z, 0, 0, 0);
            z = __builtin_amdgcn_mfma_f32_16x16x32_bf16(ak1, bq1, z, 0, 0, 0);
            sc[tt] = z;
        }
        if (k0 + 63 > qw) {
#pragma unroll
            for (int tt = 0; tt < 4; ++tt)
#pragma unroll
                for (int r = 0; r < 4; ++r)
                    if (k0 + 16 * tt + quad * 4 + r > myq) sc[tt][r] = -1e30f;
        }
        float vmax = sc[0][0];
#pragma unroll
        for (int tt = 0; tt < 4; ++tt)
#pragma unroll
            for (int r = 0; r < 4; ++r)
                vmax = fmaxf(vmax, sc[tt][r]);
        vmax = fmaxf(vmax, __shfl_xor(vmax, 16, 64));
        vmax = fmaxf(vmax, __shfl_xor(vmax, 32, 64));
        const float mnew  = fmaxf(m_i, vmax);
        const float alpha = __expf(m_i - mnew);
        m_i = mnew;
        float lsum = 0.f;
#pragma unroll
        for (int tt = 0; tt < 4; ++tt) {
            float p0 = __expf(sc[tt][0] - mnew);
            float p1 = __expf(sc[tt][1] - mnew);
            float p2 = __expf(sc[tt][2] - mnew);
            float p3 = __expf(sc[tt][3] - mnew);
            lsum += (p0 + p1) + (p2 + p3);
            ushort4 pk = {f2bf(p0), f2bf(p1), f2bf(p2), f2bf(p3)};
            *(ushort4*)&myP[col * 72 + 16 * tt + quad * 4] = pk;
        }
        lsum += __shfl_xor(lsum, 16, 64);
        lsum += __shfl_xor(lsum, 32, 64);
        l_i = l_i * alpha + lsum;
        float a_r[4];
#pragma unroll
        for (int r = 0; r < 4; ++r)
            a_r[r] = __shfl(alpha, quad * 4 + r, 64);
#pragma unroll
        for (int nt = 0; nt < 4; ++nt)
#pragma unroll
            for (int r = 0; r < 4; ++r)
                acc[nt][r] *= a_r[r];
        short8 pa0 = *(const short8*)&myP[col * 72 + quad * 8];
        short8 pa1 = *(const short8*)&myP[col * 72 + 32 + quad * 8];
#pragma unroll
        for (int nt = 0; nt < 4; ++nt) {
            short8 vb0 = *(const short8*)&sV0[nt * 512 + quad * 128 + col * 8];
            short8 vb1 = *(const short8*)&sV1[nt * 512 + quad * 128 + col * 8];
            acc[nt] = __builtin_amdgcn_mfma_f32_16x16x32_bf16(pa0, vb0, acc[nt], 0, 0, 0);
            acc[nt] = __builtin_amdgcn_mfma_f32_16x16x32_bf16(pa1, vb1, acc[nt], 0, 0, 0);
        }
        __syncthreads();
    }

    const float invl = 1.0f / l_i;
    float inv_r[4];
#pragma unroll
    for (int r = 0; r < 4; ++r)
        inv_r[r] = __shfl(invl, quad * 4 + r, 64);
#pragma unroll
    for (int nt = 0; nt < 4; ++nt)
#pragma unroll
        for (int r = 0; r < 4; ++r)
            Ctx[(size_t)(b * S_ + qw + quad * 4 + r) * HID_ + h * HD_ + nt * 16 + col] =
                f2bf(acc[nt][r] * inv_r[r]);
}

// ---------------------------------------------------------------------------
// Wo GEMM, single-K, 64x128 tiles (512 blocks), fp32 direct output.
// ---------------------------------------------------------------------------
__global__ __launch_bounds__(256) void gemm_wo(const unsigned short* __restrict__ A,
                                               const unsigned short* __restrict__ Bt,
                                               float* __restrict__ C) {
    __shared__ __align__(16) unsigned short As[64 * 32];
    __shared__ __align__(16) unsigned short Bs[128 * 32];

    const int m0 = (blockIdx.x >> 4) * 64;
    const int n0 = (blockIdx.x & 15) * 128;

    const int tid  = threadIdx.x;
    const int w    = tid >> 6;
    const int lane = tid & 63;
    const int col  = lane & 15;
    const int quad = lane >> 4;
    const int wm = (w >> 1) * 32;
    const int wn = (w & 1) * 64;

    const int lane16 = lane & 15;
    const int lchunk = lane >> 4;
    const unsigned short* Ag  = A  + (size_t)(m0 + 16 * w + lane16) * HID_ + lchunk * 8;
    const unsigned short* Bg0 = Bt + (size_t)(n0 + 16 * w + lane16) * HID_ + lchunk * 8;
    const unsigned short* Bg1 = Bt + (size_t)(n0 + 64 + 16 * w + lane16) * HID_ + lchunk * 8;

    floatx4 acc[2][4] = {};

    for (int k0 = 0; k0 < HID_; k0 += 32) {
        gl_lds16(Ag  + k0, &As[w * 512]);
        gl_lds16(Bg0 + k0, &Bs[w * 512]);
        gl_lds16(Bg1 + k0, &Bs[(4 + w) * 512]);
        __syncthreads();

        short8 af[2], bfr[4];
#pragma unroll
        for (int i = 0; i < 2; ++i)
            af[i] = *(const short8*)&As[((w >> 1) * 2 + i) * 512 + quad * 128 + col * 8];
#pragma unroll
        for (int j = 0; j < 4; ++j)
            bfr[j] = *(const short8*)&Bs[((w & 1) * 4 + j) * 512 + quad * 128 + col * 8];
#pragma unroll
        for (int i = 0; i < 2; ++i)
#pragma unroll
            for (int j = 0; j < 4; ++j)
                acc[i][j] = __builtin_amdgcn_mfma_f32_16x16x32_bf16(
                    af[i], bfr[j], acc[i][j], 0, 0, 0);
        __syncthreads();
    }

#pragma unroll
    for (int i = 0; i < 2; ++i)
#pragma unroll
        for (int j = 0; j < 4; ++j)
#pragma unroll
            for (int r = 0; r < 4; ++r)
                C[(size_t)(m0 + wm + i * 16 + quad * 4 + r) * HID_
                  + (n0 + wn + j * 16 + col)] = acc[i][j][r];
}

// ---------------------------------------------------------------------------
extern "C" void kernel_launch(void* const* d_in, const int* in_sizes, int n_in,
                              void* d_out, int out_size, void* d_ws, size_t ws_size,
                              hipStream_t stream) {
    const float* X    = (const float*)d_in[0];
    const float* cosT = (const float*)d_in[1];
    const float* sinT = (const float*)d_in[2];
    const float* Wq   = (const float*)d_in[3];
    const float* Wk   = (const float*)d_in[4];
    const float* Wv   = (const float*)d_in[5];
    const float* Wo   = (const float*)d_in[6];

    const size_t MB = 1024u * 1024u;

    // Memory schedule (ws 28 MiB, d_out 16 MiB):
    //  1 prep_all:   Xbf ws[0,8)   WcatT ws[8,20)   WoT ws[20,28)
    //  2 gemm_qkv:   reads Xbf, WcatT -> Qbf d_out[0,8), Kbf d_out[8,10),
    //                Vnat d_out[10,12)
    //  3 convert_vt: Vnat -> Vt d_out[12,14)
    //  4 attn:       reads Qbf/Kbf/Vt -> Ctxbf ws[0,8)   (Xbf dead)
    //  5 gemm_wo:    reads Ctxbf, WoT -> fp32 out d_out[0,16)  (Q/K/V dead)
    char* ws = (char*)d_ws;
    unsigned short* Xbf   = (unsigned short*)(ws);
    unsigned short* Ctxbf = (unsigned short*)(ws);
    unsigned short* WcatT = (unsigned short*)(ws + 8 * MB);
    unsigned short* WoT   = (unsigned short*)(ws + 20 * MB);
    unsigned short* Qbf   = (unsigned short*)d_out;
    unsigned short* Kbf   = (unsigned short*)((char*)d_out + 8 * MB);
    unsigned short* Vnat  = (unsigned short*)((char*)d_out + 10 * MB);
    unsigned short* Vt    = (unsigned short*)((char*)d_out + 12 * MB);
    float* out = (float*)d_out;

    // 1. prep: X->bf16, all weight transposes
    prep_all<<<14336, 256, 0, stream>>>(X, Wq, Wk, Wv, Wo, Xbf, WcatT, WoT);

    // 2. QKV projection + fused RoPE/layout (768 blocks)
    gemm_qkv<<<768, 256, 0, stream>>>(Xbf, WcatT, cosT, sinT, Qbf, Kbf, Vnat);

    // 3. V transpose (256 blocks)
    convert_vt<<<256, 256, 0, stream>>>(Vnat, Vt);

    // 4. Flash attention (load-balanced t, conflict-free LDS)
    attn_mfma<<<dim3(64, HKV_, B_), 256, 0, stream>>>(Qbf, Kbf, Vt, Ctxbf);

    // 5. Output projection (512 blocks), fp32 direct
    gemm_wo<<<512, 256, 0, stream>>>(Ctxbf, WoT, out);
}

// Round 10
// 260.773 us; speedup vs baseline: 1.0129x; 1.0129x over previous
//
#include <hip/hip_runtime.h>
#include <math.h>

#define B_   2
#define S_   1024
#define HID_ 2048
#define HQ_  32
#define HKV_ 8
#define HD_  64

using short8  = __attribute__((ext_vector_type(8))) short;
using floatx4 = __attribute__((ext_vector_type(4))) float;

__device__ __forceinline__ unsigned short f2bf(float x) {
    unsigned int u = __builtin_bit_cast(unsigned int, x);
    u += 0x7FFFu + ((u >> 16) & 1u);
    return (unsigned short)(u >> 16);
}
__device__ __forceinline__ float bf2f(unsigned short u) {
    return __builtin_bit_cast(float, (unsigned int)u << 16);
}

__device__ __forceinline__ void gl_lds16(const unsigned short* g, unsigned short* l) {
    __builtin_amdgcn_global_load_lds(
        (const __attribute__((address_space(1))) void*)g,
        (__attribute__((address_space(3))) void*)l, 16, 0, 0);
}

// ---------------------------------------------------------------------------
// PREP: convert_x (bid<4096) + transpose Wq|Wk|Wv -> WcatT (bid in [4096,10240)).
// ---------------------------------------------------------------------------
__global__ __launch_bounds__(256) void prep1(const float* __restrict__ X,
                                             const float* __restrict__ Wq,
                                             const float* __restrict__ Wk,
                                             const float* __restrict__ Wv,
                                             unsigned short* __restrict__ Xbf,
                                             unsigned short* __restrict__ WcatT) {
    __shared__ float tile[32][33];
    int bid = blockIdx.x;
    if (bid < 4096) {
        int tid = bid * 256 + threadIdx.x;
        float4 v = *(const float4*)&X[(size_t)tid * 4];
        ushort4 o = {f2bf(v.x), f2bf(v.y), f2bf(v.z), f2bf(v.w)};
        *(ushort4*)&Xbf[(size_t)tid * 4] = o;
        return;
    }
    bid -= 4096;
    const float* W;
    unsigned short* WT;
    int N, tn0, tk0;
    if (bid < 4096) {
        W = Wq; WT = WcatT; N = HID_;
        tn0 = (bid & 63) * 32; tk0 = (bid >> 6) * 32;
    } else if (bid < 5120) {
        bid -= 4096;
        W = Wk; WT = WcatT + (size_t)HID_ * HID_; N = 512;
        tn0 = (bid & 15) * 32; tk0 = (bid >> 4) * 32;
    } else {
        bid -= 5120;
        W = Wv; WT = WcatT + (size_t)(HID_ + 512) * HID_; N = 512;
        tn0 = (bid & 15) * 32; tk0 = (bid >> 4) * 32;
    }
    const int r  = threadIdx.x >> 3;
    const int c4 = (threadIdx.x & 7) * 4;
    float4 v = *(const float4*)&W[(size_t)(tk0 + r) * N + tn0 + c4];
    tile[r][c4 + 0] = v.x;
    tile[r][c4 + 1] = v.y;
    tile[r][c4 + 2] = v.z;
    tile[r][c4 + 3] = v.w;
    __syncthreads();
    ushort4 o = {f2bf(tile[c4 + 0][r]), f2bf(tile[c4 + 1][r]),
                 f2bf(tile[c4 + 2][r]), f2bf(tile[c4 + 3][r])};
    *(ushort4*)&WT[(size_t)(tn0 + r) * HID_ + tk0 + c4] = o;
}

__global__ __launch_bounds__(256) void transpose_wo(const float* __restrict__ Wo,
                                                    unsigned short* __restrict__ WoT) {
    __shared__ float tile[32][33];
    int bid = blockIdx.x;
    const int tn0 = (bid & 63) * 32;
    const int tk0 = (bid >> 6) * 32;
    const int r  = threadIdx.x >> 3;
    const int c4 = (threadIdx.x & 7) * 4;
    float4 v = *(const float4*)&Wo[(size_t)(tk0 + r) * HID_ + tn0 + c4];
    tile[r][c4 + 0] = v.x;
    tile[r][c4 + 1] = v.y;
    tile[r][c4 + 2] = v.z;
    tile[r][c4 + 3] = v.w;
    __syncthreads();
    ushort4 o = {f2bf(tile[c4 + 0][r]), f2bf(tile[c4 + 1][r]),
                 f2bf(tile[c4 + 2][r]), f2bf(tile[c4 + 3][r])};
    *(ushort4*)&WoT[(size_t)(tn0 + r) * HID_ + tk0 + c4] = o;
}

// ---------------------------------------------------------------------------
// QKV GEMM, SPLIT-K=2, 128x128, CHUNK-MAJOR LDS (conflict-free).
// bid decode as R8: bid<512 -> Q, else KV; z = high bits. bf16 partials.
// LDS: 8 regions of 16 rows (512 shorts each); region layout [chunk][row16]:
// addr = region*512 + chunk*128 + row16*8 -> b128 frag reads conflict-free.
// ---------------------------------------------------------------------------
__global__ __launch_bounds__(256) void gemm_qkv(const unsigned short* __restrict__ A,
                                                const unsigned short* __restrict__ Bt,
                                                unsigned short* __restrict__ Qp,
                                                unsigned short* __restrict__ KVp) {
    __shared__ __align__(16) unsigned short As[128 * 32];
    __shared__ __align__(16) unsigned short Bs[128 * 32];

    int bid = blockIdx.x;
    int m0, n0, z, Nw, nc0;
    unsigned short* C;
    if (bid < 512) {
        n0 = (bid & 15) * 128; m0 = ((bid >> 4) & 15) * 128; z = bid >> 8;
        C = Qp + (size_t)z * 2048 * 2048; Nw = 2048; nc0 = n0;
    } else {
        bid -= 512;
        n0 = 2048 + (bid & 7) * 128; m0 = ((bid >> 3) & 15) * 128; z = bid >> 7;
        C = KVp + (size_t)z * 2048 * 1024; Nw = 1024; nc0 = n0 - 2048;
    }
    const int kbase = z * 1024;

    const int tid  = threadIdx.x;
    const int w    = tid >> 6;
    const int lane = tid & 63;
    const int col  = lane & 15;
    const int quad = lane >> 4;
    const int wm = (w >> 1) * 64;
    const int wn = (w & 1) * 64;

    const int lane16 = lane & 15;
    const int lchunk = lane >> 4;
    const unsigned short* Ag = A  + (size_t)(m0 + 16 * w + lane16) * HID_ + lchunk * 8;
    const unsigned short* Bg = Bt + (size_t)(n0 + 16 * w + lane16) * HID_ + lchunk * 8;

    floatx4 acc[4][4] = {};

    for (int k0 = kbase; k0 < kbase + 1024; k0 += 32) {
        gl_lds16(Ag + k0,                         &As[w * 512]);
        gl_lds16(Ag + (size_t)64 * HID_ + k0,     &As[(4 + w) * 512]);
        gl_lds16(Bg + k0,                         &Bs[w * 512]);
        gl_lds16(Bg + (size_t)64 * HID_ + k0,     &Bs[(4 + w) * 512]);
        __syncthreads();

        short8 af[4], bfr[4];
#pragma unroll
        for (int i = 0; i < 4; ++i)
            af[i] = *(const short8*)&As[((w >> 1) * 4 + i) * 512 + quad * 128 + col * 8];
#pragma unroll
        for (int j = 0; j < 4; ++j)
            bfr[j] = *(const short8*)&Bs[((w & 1) * 4 + j) * 512 + quad * 128 + col * 8];
#pragma unroll
        for (int i = 0; i < 4; ++i)
#pragma unroll
            for (int j = 0; j < 4; ++j)
                acc[i][j] = __builtin_amdgcn_mfma_f32_16x16x32_bf16(
                    af[i], bfr[j], acc[i][j], 0, 0, 0);
        __syncthreads();
    }

#pragma unroll
    for (int i = 0; i < 4; ++i)
#pragma unroll
        for (int j = 0; j < 4; ++j)
#pragma unroll
            for (int r = 0; r < 4; ++r)
                C[(size_t)(m0 + wm + i * 16 + quad * 4 + r) * Nw
                  + (nc0 + wn + j * 16 + col)] = f2bf(acc[i][j][r]);
}

// ---------------------------------------------------------------------------
// Wo GEMM, SPLIT-K=2, 128x128, chunk-major LDS. z=0 -> fp32 direct; z=1 -> bf16.
// ---------------------------------------------------------------------------
__global__ __launch_bounds__(256) void gemm_wo(const unsigned short* __restrict__ A,
                                               const unsigned short* __restrict__ Bt,
                                               float* __restrict__ Cf,
                                               unsigned short* __restrict__ Cp1) {
    __shared__ __align__(16) unsigned short As[128 * 32];
    __shared__ __align__(16) unsigned short Bs[128 * 32];

    const int m0 = blockIdx.y * 128;
    const int n0 = blockIdx.x * 128;
    const int z  = blockIdx.z;
    const int kbase = z * 1024;

    const int tid  = threadIdx.x;
    const int w    = tid >> 6;
    const int lane = tid & 63;
    const int col  = lane & 15;
    const int quad = lane >> 4;
    const int wm = (w >> 1) * 64;
    const int wn = (w & 1) * 64;

    const int lane16 = lane & 15;
    const int lchunk = lane >> 4;
    const unsigned short* Ag = A  + (size_t)(m0 + 16 * w + lane16) * HID_ + lchunk * 8;
    const unsigned short* Bg = Bt + (size_t)(n0 + 16 * w + lane16) * HID_ + lchunk * 8;

    floatx4 acc[4][4] = {};

    for (int k0 = kbase; k0 < kbase + 1024; k0 += 32) {
        gl_lds16(Ag + k0,                     &As[w * 512]);
        gl_lds16(Ag + (size_t)64 * HID_ + k0, &As[(4 + w) * 512]);
        gl_lds16(Bg + k0,                     &Bs[w * 512]);
        gl_lds16(Bg + (size_t)64 * HID_ + k0, &Bs[(4 + w) * 512]);
        __syncthreads();

        short8 af[4], bfr[4];
#pragma unroll
        for (int i = 0; i < 4; ++i)
            af[i] = *(const short8*)&As[((w >> 1) * 4 + i) * 512 + quad * 128 + col * 8];
#pragma unroll
        for (int j = 0; j < 4; ++j)
            bfr[j] = *(const short8*)&Bs[((w & 1) * 4 + j) * 512 + quad * 128 + col * 8];
#pragma unroll
        for (int i = 0; i < 4; ++i)
#pragma unroll
            for (int j = 0; j < 4; ++j)
                acc[i][j] = __builtin_amdgcn_mfma_f32_16x16x32_bf16(
                    af[i], bfr[j], acc[i][j], 0, 0, 0);
        __syncthreads();
    }

#pragma unroll
    for (int i = 0; i < 4; ++i)
#pragma unroll
        for (int j = 0; j < 4; ++j)
#pragma unroll
            for (int r = 0; r < 4; ++r) {
                size_t off = (size_t)(m0 + wm + i * 16 + quad * 4 + r) * HID_
                           + (n0 + wn + j * 16 + col);
                if (z == 0) Cf[off] = acc[i][j][r];
                else        Cp1[off] = f2bf(acc[i][j][r]);
            }
}

// out[i] += bf2f(p1[i]), vectorized. 4096 blocks x 256.
__global__ __launch_bounds__(256) void reduce_wo(float* __restrict__ out,
                                                 const unsigned short* __restrict__ p1) {
    int i4 = (blockIdx.x * 256 + threadIdx.x) * 4;
    float4 o = *(float4*)&out[i4];
    ushort4 p = *(const ushort4*)&p1[i4];
    o.x += bf2f(p.x); o.y += bf2f(p.y); o.z += bf2f(p.z); o.w += bf2f(p.w);
    *(float4*)&out[i4] = o;
}

// ---------------------------------------------------------------------------
// Fused split-K reduce + RoPE + layout conversion (unchanged from R8).
// ---------------------------------------------------------------------------
__global__ __launch_bounds__(256) void convert_qkv(const unsigned short* __restrict__ Qp,
                                                   const unsigned short* __restrict__ KVp,
                                                   const float* __restrict__ cosT,
                                                   const float* __restrict__ sinT,
                                                   unsigned short* __restrict__ Qbf,
                                                   unsigned short* __restrict__ Kbf,
                                                   unsigned short* __restrict__ Vt) {
    const size_t QSTR  = (size_t)2048 * 2048;
    const size_t KVSTR = (size_t)2048 * 1024;
    int tid = blockIdx.x * 256 + threadIdx.x;
    const int NQ = B_ * S_ * HQ_ * 32;
    const int NK = B_ * S_ * HKV_ * 32;
    if (tid < NQ) {
        int d = tid & 31;
        int h = (tid >> 5) & (HQ_ - 1);
        int s = (tid >> 10) & (S_ - 1);
        int b = tid >> 20;
        const unsigned short* row = Qp + (size_t)(b * S_ + s) * 2048 + h * HD_;
        float x0 = bf2f(row[d])      + bf2f(row[QSTR + d]);
        float x1 = bf2f(row[d + 32]) + bf2f(row[QSTR + d + 32]);
        float c0 = cosT[s * HD_ + d],      s0 = sinT[s * HD_ + d];
        float c1 = cosT[s * HD_ + d + 32], s1 = sinT[s * HD_ + d + 32];
        unsigned short* orow = Qbf + ((size_t)(b * HQ_ + h) * S_ + s) * HD_;
        orow[d]      = f2bf((x0 * c0 - x1 * s0) * 0.125f);
        orow[d + 32] = f2bf((x1 * c1 + x0 * s1) * 0.125f);
    } else if (tid < NQ + NK) {
        tid -= NQ;
        int d  = tid & 31;
        int kv = (tid >> 5) & (HKV_ - 1);
        int s  = (tid >> 8) & (S_ - 1);
        int b  = tid >> 18;
        const unsigned short* row = KVp + (size_t)(b * S_ + s) * 1024 + kv * HD_;
        float x0 = bf2f(row[d])      + bf2f(row[KVSTR + d]);
        float x1 = bf2f(row[d + 32]) + bf2f(row[KVSTR + d + 32]);
        float c0 = cosT[s * HD_ + d],      s0 = sinT[s * HD_ + d];
        float c1 = cosT[s * HD_ + d + 32], s1 = sinT[s * HD_ + d + 32];
        unsigned short* orow = Kbf + ((size_t)(b * HKV_ + kv) * S_ + s) * HD_;
        orow[d]      = f2bf(x0 * c0 - x1 * s0);
        orow[d + 32] = f2bf(x1 * c1 + x0 * s1);
    } else {
        tid -= NQ + NK;
        int s4 = tid & 255;
        int d  = (tid >> 8) & (HD_ - 1);
        int kv = (tid >> 14) & (HKV_ - 1);
        int b  = tid >> 17;
        int s  = s4 * 4;
        const unsigned short* base =
            KVp + ((size_t)(b * S_ + s)) * 1024 + 512 + kv * HD_ + d;
        ushort4 o;
#pragma unroll
        for (int j = 0; j < 4; ++j) {
            float v = bf2f(base[(size_t)j * 1024]) +
                      bf2f(base[KVSTR + (size_t)j * 1024]);
            ((unsigned short*)&o)[j] = f2bf(v);
        }
        *(ushort4*)&Vt[((size_t)(b * HKV_ + kv) * HD_ + d) * S_ + s] = o;
    }
}

// ---------------------------------------------------------------------------
// Flash attention (R9 version: t-scrambled load balance + chunk-major LDS).
// ---------------------------------------------------------------------------
__global__ __launch_bounds__(256) void attn_mfma(const unsigned short* __restrict__ Qbf,
                                                 const unsigned short* __restrict__ Kbf,
                                                 const unsigned short* __restrict__ Vt,
                                                 unsigned short* __restrict__ Ctx) {
    const int t = 63 - ((blockIdx.x + 4 * (blockIdx.y + 8 * blockIdx.z)) & 63);
    const int kv = blockIdx.y;
    const int b  = blockIdx.z;
    const int w    = threadIdx.x >> 6;
    const int lane = threadIdx.x & 63;
    const int col  = lane & 15;
    const int quad = lane >> 4;

    const int h   = kv * 4 + w;
    const int bh  = b * HQ_ + h;
    const int bkv = b * HKV_ + kv;
    const int qw  = 16 * t;
    const int myq = qw + col;

    __shared__ __align__(16) unsigned short sK0[64 * 32];
    __shared__ __align__(16) unsigned short sK1[64 * 32];
    __shared__ __align__(16) unsigned short sV0[64 * 32];
    __shared__ __align__(16) unsigned short sV1[64 * 32];
    __shared__ __align__(16) unsigned short sP[4][16 * 72];
    unsigned short* myP = sP[w];

    const unsigned short* qrow = Qbf + ((size_t)bh * S_ + qw + col) * HD_;
    short8 bq0 = *(const short8*)&qrow[quad * 8];
    short8 bq1 = *(const short8*)&qrow[32 + quad * 8];

    const int lane16 = lane & 15;
    const int lchunk = lane >> 4;
    const unsigned short* KbL =
        Kbf + (size_t)bkv * S_ * HD_ + (size_t)(16 * w + lane16) * HD_ + lchunk * 8;
    const unsigned short* VbL =
        Vt + (size_t)bkv * HD_ * S_ + (size_t)(16 * w + lane16) * S_ + lchunk * 8;

    floatx4 acc[4] = {};
    float m_i = -1e30f, l_i = 0.f;
    const int nsteps = (16 * t + 79) >> 6;

    for (int it = 0; it < nsteps; ++it) {
        const int k0 = it * 64;
        gl_lds16(KbL + (size_t)k0 * HD_,      &sK0[w * 512]);
        gl_lds16(KbL + (size_t)k0 * HD_ + 32, &sK1[w * 512]);
        gl_lds16(VbL + k0,                    &sV0[w * 512]);
        gl_lds16(VbL + k0 + 32,               &sV1[w * 512]);
        __syncthreads();

        floatx4 sc[4];
#pragma unroll
        for (int tt = 0; tt < 4; ++tt) {
            short8 ak0 = *(const short8*)&sK0[tt * 512 + quad * 128 + col * 8];
            short8 ak1 = *(const short8*)&sK1[tt * 512 + quad * 128 + col * 8];
            floatx4 z = {0.f, 0.f, 0.f, 0.f};
            z = __builtin_amdgcn_mfma_f32_16x16x32_bf16(ak0, bq0, z, 0, 0, 0);
            z = __builtin_amdgcn_mfma_f32_16x16x32_bf16(ak1, bq1, z, 0, 0, 0);
            sc[tt] = z;
        }
        if (k0 + 63 > qw) {
#pragma unroll
            for (int tt = 0; tt < 4; ++tt)
#pragma unroll
                for (int r = 0; r < 4; ++r)
                    if (k0 + 16 * tt + quad * 4 + r > myq) sc[tt][r] = -1e30f;
        }
        float vmax = sc[0][0];
#pragma unroll
        for (int tt = 0; tt < 4; ++tt)
#pragma unroll
            for (int r = 0; r < 4; ++r)
                vmax = fmaxf(vmax, sc[tt][r]);
        vmax = fmaxf(vmax, __shfl_xor(vmax, 16, 64));
        vmax = fmaxf(vmax, __shfl_xor(vmax, 32, 64));
        const float mnew  = fmaxf(m_i, vmax);
        const float alpha = __expf(m_i - mnew);
        m_i = mnew;
        float lsum = 0.f;
#pragma unroll
        for (int tt = 0; tt < 4; ++tt) {
            float p0 = __expf(sc[tt][0] - mnew);
            float p1 = __expf(sc[tt][1] - mnew);
            float p2 = __expf(sc[tt][2] - mnew);
            float p3 = __expf(sc[tt][3] - mnew);
            lsum += (p0 + p1) + (p2 + p3);
            ushort4 pk = {f2bf(p0), f2bf(p1), f2bf(p2), f2bf(p3)};
            *(ushort4*)&myP[col * 72 + 16 * tt + quad * 4] = pk;
        }
        lsum += __shfl_xor(lsum, 16, 64);
        lsum += __shfl_xor(lsum, 32, 64);
        l_i = l_i * alpha + lsum;
        float a_r[4];
#pragma unroll
        for (int r = 0; r < 4; ++r)
            a_r[r] = __shfl(alpha, quad * 4 + r, 64);
#pragma unroll
        for (int nt = 0; nt < 4; ++nt)
#pragma unroll
            for (int r = 0; r < 4; ++r)
                acc[nt][r] *= a_r[r];
        short8 pa0 = *(const short8*)&myP[col * 72 + quad * 8];
        short8 pa1 = *(const short8*)&myP[col * 72 + 32 + quad * 8];
#pragma unroll
        for (int nt = 0; nt < 4; ++nt) {
            short8 vb0 = *(const short8*)&sV0[nt * 512 + quad * 128 + col * 8];
            short8 vb1 = *(const short8*)&sV1[nt * 512 + quad * 128 + col * 8];
            acc[nt] = __builtin_amdgcn_mfma_f32_16x16x32_bf16(pa0, vb0, acc[nt], 0, 0, 0);
            acc[nt] = __builtin_amdgcn_mfma_f32_16x16x32_bf16(pa1, vb1, acc[nt], 0, 0, 0);
        }
        __syncthreads();
    }

    const float invl = 1.0f / l_i;
    float inv_r[4];
#pragma unroll
    for (int r = 0; r < 4; ++r)
        inv_r[r] = __shfl(invl, quad * 4 + r, 64);
#pragma unroll
    for (int nt = 0; nt < 4; ++nt)
#pragma unroll
        for (int r = 0; r < 4; ++r)
            Ctx[(size_t)(b * S_ + qw + quad * 4 + r) * HID_ + h * HD_ + nt * 16 + col] =
                f2bf(acc[nt][r] * inv_r[r]);
}

// ---------------------------------------------------------------------------
extern "C" void kernel_launch(void* const* d_in, const int* in_sizes, int n_in,
                              void* d_out, int out_size, void* d_ws, size_t ws_size,
                              hipStream_t stream) {
    const float* X    = (const float*)d_in[0];
    const float* cosT = (const float*)d_in[1];
    const float* sinT = (const float*)d_in[2];
    const float* Wq   = (const float*)d_in[3];
    const float* Wk   = (const float*)d_in[4];
    const float* Wv   = (const float*)d_in[5];
    const float* Wo   = (const float*)d_in[6];

    const int M = B_ * S_;          // 2048
    const size_t MB = 1024u * 1024u;

    // Memory schedule (ws 28 MiB, d_out 16 MiB), R8 lifetimes:
    //  1 prep1:        Xbf ws[0,8), WcatT ws[8,20)
    //  2 gemm_qkv:     Q partials (2x8 MiB) -> d_out; KV partials -> ws[20,28)
    //  3 convert_qkv:  Qbf ws[0,8), Kbf ws[8,10), Vt ws[10,12)
    //  4 transpose_wo: WoT -> ws[12,20)
    //  5 attn:         Ctxbf -> ws[20,28)
    //  6 gemm_wo:      z=0 fp32 -> d_out; z=1 bf16 p1 -> ws[0,8)
    //  7 reduce_wo:    d_out += p1
    char* ws = (char*)d_ws;
    unsigned short* Xbf   = (unsigned short*)(ws);
    unsigned short* Qbf   = (unsigned short*)(ws);
    unsigned short* WcatT = (unsigned short*)(ws + 8 * MB);
    unsigned short* Kbf   = (unsigned short*)(ws + 8 * MB);
    unsigned short* Vt    = (unsigned short*)(ws + 10 * MB);
    unsigned short* WoT   = (unsigned short*)(ws + 12 * MB);
    unsigned short* KVp   = (unsigned short*)(ws + 20 * MB);
    unsigned short* Ctxbf = (unsigned short*)(ws + 20 * MB);
    unsigned short* Wop1  = (unsigned short*)(ws);
    unsigned short* Qp    = (unsigned short*)d_out;
    float* out = (float*)d_out;

    // 1. prep: X->bf16 + Wq|Wk|Wv transpose
    prep1<<<10240, 256, 0, stream>>>(X, Wq, Wk, Wv, Xbf, WcatT);

    // 2. QKV projection, split-K=2, conflict-free LDS (768 blocks)
    gemm_qkv<<<768, 256, 0, stream>>>(Xbf, WcatT, Qp, KVp);

    // 3. Fused split-K reduce + RoPE + layout conversion
    {
        int total = B_ * S_ * HQ_ * 32 + B_ * S_ * HKV_ * 32
                  + B_ * HKV_ * HD_ * (S_ / 4);
        convert_qkv<<<total / 256, 256, 0, stream>>>(Qp, KVp, cosT, sinT,
                                                     Qbf, Kbf, Vt);
    }

    // 4. Wo -> WoT
    transpose_wo<<<4096, 256, 0, stream>>>(Wo, WoT);

    // 5. Flash attention (load-balanced, conflict-free)
    attn_mfma<<<dim3(64, HKV_, B_), 256, 0, stream>>>(Qbf, Kbf, Vt, Ctxbf);

    // 6. Output projection, split-K=2, conflict-free LDS (512 blocks)
    gemm_wo<<<dim3(16, 16, 2), 256, 0, stream>>>(Ctxbf, WoT, out, Wop1);

    // 7. out += p1
    reduce_wo<<<(M * HID_ / 4) / 256, 256, 0, stream>>>(out, Wop1);
}